// Round 7
// baseline (708.648 us; speedup 1.0000x reference)
//
#include <hip/hip_runtime.h>
#include <cstdint>
#include <cstddef>

// Problem constants
#define M_DIM 8192
#define N_DIM 4096
#define K_DIM 4096

using i32x4 = __attribute__((ext_vector_type(4))) int;

// Pack int32 values (range [-128,127]) to int8 for BOTH x and w in one dispatch.
__global__ __launch_bounds__(256) void pack_i8_fused_kernel(const int4* __restrict__ xsrc,
                                                            const int4* __restrict__ wsrc,
                                                            unsigned* __restrict__ xdst,
                                                            unsigned* __restrict__ wdst,
                                                            long nx4, long ntot4) {
    long i = (long)blockIdx.x * blockDim.x + threadIdx.x;
    if (i >= ntot4) return;
    const int4* src;
    unsigned* dst;
    long si;
    if (i < nx4) { src = xsrc; dst = xdst; si = i; }
    else         { src = wsrc; dst = wdst; si = i - nx4; }
    int4 a = src[si];
    dst[si] = (unsigned)((a.x & 0xff) | ((a.y & 0xff) << 8) |
                         ((a.z & 0xff) << 16) | (a.w << 24));
}

// C[m][n] = sum_k A[m][k]*B[n][k]  (both K-contiguous, int8), then
// out = clamp(round((acc + bias[n]) * (0.05*wscale[n]/0.1)), -128, 127) as int32.
//
// LDS-FREE (flatmm-style): each wave loads its MFMA fragments directly
// global->VGPR. The fragment gather (16 rows x 64B full lines per
// instruction) is the SAME pattern the LDS staging used, so per-line
// traffic is identical; sibling-wave duplication (2x) is absorbed by
// L1/L2. No __syncthreads in the K-loop => no vmcnt(0) barrier drain,
// no block convoy (R3-R6 plateaued at MfmaUtil ~34% = single-block
// compute fraction because co-resident blocks drained in lockstep).
// Register double-buffer: fragments for step k+1 load while step k's
// 16 MFMAs issue; compiler inserts fine-grained vmcnt waits.
__global__ __launch_bounds__(256) void qgemm_i8_kernel(const int8_t* __restrict__ A,
                                                       const int8_t* __restrict__ B,
                                                       const int* __restrict__ bias,
                                                       const float* __restrict__ wscale,
                                                       int* __restrict__ C) {
    const int tid  = threadIdx.x;
    const int wave = tid >> 6;
    const int lane = tid & 63;
    const int bm = blockIdx.y;
    const int bn = blockIdx.x;

    const int wm = wave >> 1;   // 0..1 : row half of 128x128 block tile
    const int wn = wave & 1;    // 0..1 : col half

    // fragment geometry (mfma_i32_16x16x64_i8): m/n = lane&15, 16B of K per
    // lane at chunk lane>>4. Frag i/j adds i*16 rows.
    const int l15 = lane & 15;
    const int kq  = (lane >> 4) * 16;

    const int8_t* Ap = A + (size_t)(bm * 128 + wm * 64 + l15) * K_DIM + kq;
    const int8_t* Bp = B + (size_t)(bn * 128 + wn * 64 + l15) * K_DIM + kq;

    i32x4 acc[4][4] = {};        // 16 independent accumulators
    i32x4 af[2][4], bf[2][4];    // 2-deep register pipeline of fragments

    auto ldfrags = [&](int kt, int s) {
#pragma unroll
        for (int i = 0; i < 4; ++i)
            af[s][i] = *(const i32x4*)(Ap + (size_t)i * (16 * K_DIM) + kt);
#pragma unroll
        for (int j = 0; j < 4; ++j)
            bf[s][j] = *(const i32x4*)(Bp + (size_t)j * (16 * K_DIM) + kt);
    };

    auto domfma = [&](int s) {
#pragma unroll
        for (int i = 0; i < 4; ++i)
#pragma unroll
            for (int j = 0; j < 4; ++j)
                acc[i][j] = __builtin_amdgcn_mfma_i32_16x16x64_i8(
                    af[s][i], bf[s][j], acc[i][j], 0, 0, 0);
    };

    ldfrags(0, 0);
    // 64 K-steps of 64, unrolled x2 so pipeline slots are compile-time.
    for (int kt = 0; kt < K_DIM; kt += 128) {
        ldfrags(kt + 64, 1);          // kt+64 <= 4032, always in range
        domfma(0);
        const int ktn = kt + 128;
        if (ktn < K_DIM) ldfrags(ktn, 0);
        domfma(1);
    }

    // Epilogue. 16x16 C/D layout: col = lane&15, row = (lane>>4)*4 + reg
    const int col16 = lane & 15;
    const int rquad = (lane >> 4) * 4;
#pragma unroll
    for (int j = 0; j < 4; ++j) {
        const int col = bn * 128 + wn * 64 + j * 16 + col16;
        float s = 0.05f * wscale[col];
        s = s / 0.1f;                      // match np ref arithmetic exactly
        const float bz = (float)bias[col];
#pragma unroll
        for (int i = 0; i < 4; ++i) {
            const int row0 = bm * 128 + wm * 64 + i * 16 + rquad;
#pragma unroll
            for (int r = 0; r < 4; ++r) {
                float v = ((float)acc[i][j][r] + bz) * s;
                v = rintf(v);              // RTNE, matches np.round
                v = fminf(fmaxf(v, -128.0f), 127.0f);
                C[(size_t)(row0 + r) * N_DIM + col] = (int)v;
            }
        }
    }
}

extern "C" void kernel_launch(void* const* d_in, const int* in_sizes, int n_in,
                              void* d_out, int out_size, void* d_ws, size_t ws_size,
                              hipStream_t stream) {
    const int*   x32    = (const int*)d_in[0];     // int8 values promoted to int32
    const int*   w32    = (const int*)d_in[1];
    const int*   bias   = (const int*)d_in[2];
    const float* wscale = (const float*)d_in[3];
    int*         out    = (int*)d_out;

    int8_t* xp = (int8_t*)d_ws;                         // 32 MiB packed x
    int8_t* wp = xp + (size_t)M_DIM * K_DIM;            // 16 MiB packed w

    {
        long nx4   = (long)M_DIM * K_DIM / 4;
        long nw4   = (long)N_DIM * K_DIM / 4;
        long ntot4 = nx4 + nw4;
        pack_i8_fused_kernel<<<(int)((ntot4 + 255) / 256), 256, 0, stream>>>(
            (const int4*)x32, (const int4*)w32,
            (unsigned*)xp, (unsigned*)wp, nx4, ntot4);
    }

    dim3 grid(N_DIM / 128, M_DIM / 128);   // (32, 64)
    qgemm_i8_kernel<<<grid, 256, 0, stream>>>(xp, wp, bias, wscale, out);
}